// Round 6
// baseline (312.268 us; speedup 1.0000x reference)
//
#include <hip/hip_runtime.h>
#include <cstdint>

// Problem: B=4, S=2048, D_MODEL=1024, H=16, depth=64.
// Pipeline: pack x->bf16 + pack/transpose W->bf16 [N][K] (one launch);
// QKV GEMM (bf16 MFMA, fp32 acc, single-barrier double-buffered K-loop,
// C^T orientation for Q/K -> vectorized stores) -> Q[bh,s,d] (pre-scaled by
// log2e/8), K[bh,s,d], Vt[bh,d,s'] key-permuted; flash attention: BARRIER-FREE
// zero-LDS register streaming, 64 q-rows/wave, direct global->VGPR fragments;
// out GEMM (C^T, float4) -> fp32.

typedef __bf16 bf16x8 __attribute__((ext_vector_type(8)));
typedef float f32x4 __attribute__((ext_vector_type(4)));
typedef int i32x4 __attribute__((ext_vector_type(4)));

#define CEXP 0.18033688011112042f  // (1/8) * log2(e), folded into Q

__device__ __forceinline__ unsigned short f2bf(float f) {
  union { float f; unsigned int u; } v; v.f = f;
  unsigned int r = v.u + 0x7FFFu + ((v.u >> 16) & 1u);  // RNE
  return (unsigned short)(r >> 16);
}
__device__ __forceinline__ unsigned int fbits(float f) {
  union { float f; unsigned int u; } v; v.f = f; return v.u;
}

// pack two f32 -> one int holding (bf16(b)<<16)|bf16(a)
__device__ __forceinline__ int pkbf16(float a, float b) {
#if __has_builtin(__builtin_amdgcn_cvt_pk_bf16_f32)
  auto r = __builtin_amdgcn_cvt_pk_bf16_f32(a, b);  // lo=cvt(a), hi=cvt(b), RNE
  return __builtin_bit_cast(int, r);
#else
  return (int)__builtin_amdgcn_perm(fbits(b) + 0x8000u, fbits(a) + 0x8000u, 0x07060302u);
#endif
}

// async global->LDS, 16B per lane. LDS dest = wave-uniform base + lane*16.
__device__ __forceinline__ void gl_lds16(const void* g, void* l) {
  __builtin_amdgcn_global_load_lds(
      (const __attribute__((address_space(1))) void*)(unsigned long long)g,
      (__attribute__((address_space(3))) void*)(unsigned int)(unsigned long long)l,
      16, 0, 0);
}

// ---------------- pack x (fp32 -> bf16) + pack/transpose weights ----------------
__global__ __launch_bounds__(256) void pack_all_kernel(const float* __restrict__ x,
                                                       const float* __restrict__ wq,
                                                       const float* __restrict__ wk,
                                                       const float* __restrict__ wv,
                                                       const float* __restrict__ wo,
                                                       unsigned short* __restrict__ xb,
                                                       unsigned short* __restrict__ wqkvt,
                                                       unsigned short* __restrict__ wot) {
  int bid = blockIdx.x;
  if (bid < 8192) {  // pack x
    int i = (bid * 256 + threadIdx.x) * 4;
    float4 v = *(const float4*)(x + i);
    unsigned int lo = (unsigned int)f2bf(v.x) | ((unsigned int)f2bf(v.y) << 16);
    unsigned int hi = (unsigned int)f2bf(v.z) | ((unsigned int)f2bf(v.w) << 16);
    uint2 st; st.x = lo; st.y = hi;
    *(uint2*)(xb + i) = st;
    return;
  }
  // pack + transpose weights: Wt[n][k] = w[k][n]
  __shared__ unsigned short T[64 * 66];  // +2 pad: conflict-free
  bid -= 8192;
  int mat = bid >> 8;                    // 0..3 = wq,wk,wv,wo
  int tile = bid & 255;
  int tk = tile >> 4, tn = tile & 15;    // 64x64 tiles
  const float* W = (mat == 0) ? wq : (mat == 1) ? wk : (mat == 2) ? wv : wo;
  int t = threadIdx.x;
#pragma unroll
  for (int p = 0; p < 16; ++p) {
    int e = p * 256 + t;
    int r = e >> 6, c = e & 63;
    T[c * 66 + r] = f2bf(W[(tk * 64 + r) * 1024 + tn * 64 + c]);
  }
  __syncthreads();
  unsigned short* dst = (mat < 3) ? (wqkvt + mat * 1024 * 1024) : wot;
#pragma unroll
  for (int p = 0; p < 16; ++p) {
    int e = p * 256 + t;
    int nn = e >> 6, kk = e & 63;
    dst[(tn * 64 + nn) * 1024 + tk * 64 + kk] = T[nn * 66 + kk];
  }
}

// stage one 128x64 A-tile and 128x64 B-tile (swizzled) via global_load_lds
__device__ __forceinline__ void stage_tile(const unsigned short* __restrict__ Ag,
                                           const unsigned short* __restrict__ Bg,
                                           unsigned short* As, unsigned short* Bs,
                                           int t, int wave) {
#pragma unroll
  for (int p = 0; p < 4; ++p) {
    int s = p * 256 + t;
    int row = s >> 3;
    int cc = (s & 7) ^ (row & 7);
    gl_lds16(Ag + row * 1024 + cc * 8, (void*)(As + (p * 256 + wave * 64) * 8));
    gl_lds16(Bg + row * 1024 + cc * 8, (void*)(Bs + (p * 256 + wave * 64) * 8));
  }
}

// K-loop: acc = A-tile x B-tile^T over K=1024. TRANS=1 computes C^T
// (lane = m-row, regs = 4 consecutive n) for vectorized epilogue stores.
template <int TRANS>
__device__ __forceinline__ void kloop(const unsigned short* __restrict__ Ab,
                                      const unsigned short* __restrict__ Bb,
                                      unsigned short* S, f32x4 acc[4][4],
                                      int t, int wave, int l15, int quad,
                                      int wm, int wn, int Xo0, int Xo1) {
  stage_tile(Ab, Bb, S, S + 8192, t, wave);  // tile 0 -> buf 0
  for (int k0 = 0; k0 < 1024; k0 += 64) {
    const int buf = (k0 >> 6) & 1;
    unsigned short* Sc = S + buf * 16384;
    __syncthreads();  // drains buf's loads (issued one full iteration ago)
    if (k0 < 1024 - 64) {
      unsigned short* Sn = S + (buf ^ 1) * 16384;
      stage_tile(Ab + k0 + 64, Bb + k0 + 64, Sn, Sn + 8192, t, wave);
    }
#pragma unroll
    for (int kc = 0; kc < 2; ++kc) {
      const int Xo = kc ? Xo1 : Xo0;
      bf16x8 af[4], bfr[4];
#pragma unroll
      for (int mi = 0; mi < 4; ++mi)
        af[mi] = *(const bf16x8*)&Sc[(wm * 64 + mi * 16 + l15) * 64 + Xo];
#pragma unroll
      for (int ni = 0; ni < 4; ++ni)
        bfr[ni] = *(const bf16x8*)&Sc[8192 + (wn * 64 + ni * 16 + l15) * 64 + Xo];
#pragma unroll
      for (int mi = 0; mi < 4; ++mi)
#pragma unroll
        for (int ni = 0; ni < 4; ++ni)
          acc[mi][ni] = TRANS
              ? __builtin_amdgcn_mfma_f32_16x16x32_bf16(bfr[ni], af[mi], acc[mi][ni], 0, 0, 0)
              : __builtin_amdgcn_mfma_f32_16x16x32_bf16(af[mi], bfr[ni], acc[mi][ni], 0, 0, 0);
    }
  }
}

// ---------------- GEMM: C[M][N] = A[M][1024] * Bt[N][1024]^T ----------------
// MODE 0: QKV epilogue (bias + scatter bf16 to Q/K/Vt; Q pre-scaled by CEXP;
//         Vt key order permuted within 64-blocks).  MODE 1: fp32 out + bias.
template <int MODE>
__global__ __launch_bounds__(256) void gemm_bt_kernel(
    const unsigned short* __restrict__ A, const unsigned short* __restrict__ Bt,
    const float* __restrict__ b0, const float* __restrict__ b1, const float* __restrict__ b2,
    unsigned short* __restrict__ Qg, unsigned short* __restrict__ Kg,
    unsigned short* __restrict__ Vtg, float* __restrict__ Of) {
  __shared__ __align__(16) unsigned short S[32768];  // 64KB: [buf][A 8192 | B 8192]
  const int t = threadIdx.x;
  const int lane = t & 63, wave = t >> 6;
  const int l15 = lane & 15, quad = lane >> 4;
  const int wm = wave & 1, wn = wave >> 1;
  const int m0 = blockIdx.x * 128, n0 = blockIdx.y * 128;
  const unsigned short* Ab = A + (size_t)m0 * 1024;
  const unsigned short* Bb = Bt + (size_t)n0 * 1024;
  const int seg = (MODE == 0) ? (blockIdx.y >> 3) : 0;  // 0=Q,1=K,2=V

  f32x4 acc[4][4];
#pragma unroll
  for (int i = 0; i < 4; ++i)
#pragma unroll
    for (int j = 0; j < 4; ++j) acc[i][j] = (f32x4){0.f, 0.f, 0.f, 0.f};

  const int Xo0 = ((quad ^ (l15 & 7)) * 8);
  const int Xo1 = (((4 + quad) ^ (l15 & 7)) * 8);

  if (MODE == 1 || seg < 2) {  // block-uniform branch
    kloop<1>(Ab, Bb, S, acc, t, wave, l15, quad, wm, wn, Xo0, Xo1);
    if (MODE == 0) {
      // C^T: lane=m (s row), regs = 4 consecutive n (d) -> 8B stores
      const float* bias = (seg == 0) ? b0 : b1;
      unsigned short* qk = (seg == 0) ? Qg : Kg;
      const int m = m0 + wm * 64 + l15;
#pragma unroll
      for (int mi = 0; mi < 4; ++mi) {
        int mm = m + mi * 16;
        int b = mm >> 11, s = mm & 2047;
#pragma unroll
        for (int ni = 0; ni < 4; ++ni) {
          int nb = n0 + wn * 64 + ni * 16 + quad * 4;
          int nn = nb & 1023;
          float4 bb = *(const float4*)(bias + nn);
          int h = nn >> 6, d = nn & 63;
          float v0 = acc[mi][ni][0] + bb.x, v1 = acc[mi][ni][1] + bb.y;
          float v2 = acc[mi][ni][2] + bb.z, v3 = acc[mi][ni][3] + bb.w;
          if (seg == 0) { v0 *= CEXP; v1 *= CEXP; v2 *= CEXP; v3 *= CEXP; }
          uint2 st;
          st.x = (unsigned int)pkbf16(v0, v1);
          st.y = (unsigned int)pkbf16(v2, v3);
          *(uint2*)(qk + ((size_t)((b * 16 + h) * 2048 + s)) * 64 + d) = st;
        }
      }
    } else {
      // out-proj: float4 stores to Of[m][n..n+3]
      const int m = m0 + wm * 64 + l15;
#pragma unroll
      for (int mi = 0; mi < 4; ++mi) {
        int mm = m + mi * 16;
#pragma unroll
        for (int ni = 0; ni < 4; ++ni) {
          int n = n0 + wn * 64 + ni * 16 + quad * 4;
          float4 bb = *(const float4*)(b0 + n);
          float4 st;
          st.x = acc[mi][ni][0] + bb.x; st.y = acc[mi][ni][1] + bb.y;
          st.z = acc[mi][ni][2] + bb.z; st.w = acc[mi][ni][3] + bb.w;
          *(float4*)(Of + (size_t)mm * 1024 + n) = st;
        }
      }
    }
  } else {  // V: normal orientation; regs = 4 consecutive permuted key slots
    kloop<0>(Ab, Bb, S, acc, t, wave, l15, quad, wm, wn, Xo0, Xo1);
#pragma unroll
    for (int ni = 0; ni < 4; ++ni) {
      int n = n0 + wn * 64 + ni * 16 + l15;
      int nn = n & 1023;
      int h = nn >> 6, d = nn & 63;
      float bb = b2[nn];
#pragma unroll
      for (int mi = 0; mi < 4; ++mi) {
        int mb = m0 + wm * 64 + mi * 16 + quad * 4;
        int b = mb >> 11, s0 = mb & 2047;
        // key permutation keeps low 2 bits: 4 consecutive slots
        int sp0 = (s0 & ~63) | (s0 & 32) | ((s0 & 12) << 1) | ((s0 & 16) >> 2);
        float v0 = acc[mi][ni][0] + bb, v1 = acc[mi][ni][1] + bb;
        float v2 = acc[mi][ni][2] + bb, v3 = acc[mi][ni][3] + bb;
        uint2 st;
        st.x = (unsigned int)pkbf16(v0, v1);
        st.y = (unsigned int)pkbf16(v2, v3);
        *(uint2*)(Vtg + ((size_t)((b * 16 + h) * 64 + d)) * 2048 + sp0) = st;
      }
    }
  }
}

// ---------------- flash attention: barrier-free, zero-LDS, 64 q/wave ----------------
// grid: 512 blocks = 64 bh x 8 q-tiles of 256; 4 waves, wave owns 64 q rows.
// All MFMA fragments loaded directly global->VGPR (dwordx4); K/V tiles shared
// across the block's waves through L1. No __syncthreads anywhere.
// Per kt (64 keys): S^T = K*Q^T per qi (4x16 q cols); p = exp2(s) (scale
// pre-folded into Q); P^T packed in regs = PV B-operand (V^T global key order
// pre-permuted so direct A-operand loads line up); O^T += V^T * P^T.
__global__ __launch_bounds__(256) void attn_kernel(const unsigned short* __restrict__ Qg,
                                                   const unsigned short* __restrict__ Kg,
                                                   const unsigned short* __restrict__ Vtg,
                                                   unsigned short* __restrict__ Og) {
  const int t = threadIdx.x;
  const int lane = t & 63, wave = t >> 6;
  const int l15 = lane & 15, quad = lane >> 4;
  const int bid = blockIdx.x;
  const int bh = (bid & 7) * 8 + (bid >> 6);  // XCD-affinity: same bh -> same XCD
  const int qt = (bid >> 3) & 7;
  const int q0 = qt * 256 + wave * 64;

  // per-lane row bases (elements)
  const unsigned short* Qrow = Qg + ((size_t)bh * 2048 + q0) * 64 + l15 * 64 + quad * 8;
  const unsigned short* Krow = Kg + (size_t)bh * 2048 * 64 + l15 * 64 + quad * 8;
  const unsigned short* Vrow = Vtg + (size_t)bh * 64 * 2048 + l15 * 2048 + quad * 8;

  // loop-invariant Q fragments (B-operand: lane=q, elems=d)
  bf16x8 qf[4][2];
#pragma unroll
  for (int qi = 0; qi < 4; ++qi)
#pragma unroll
    for (int kc = 0; kc < 2; ++kc)
      qf[qi][kc] = *(const bf16x8*)(Qrow + qi * 1024 + kc * 32);

  // preload K/V tile 0 fragments
  bf16x8 kf[4][2], vf[4][2];
#pragma unroll
  for (int ki = 0; ki < 4; ++ki)
#pragma unroll
    for (int kc = 0; kc < 2; ++kc)
      kf[ki][kc] = *(const bf16x8*)(Krow + ki * 1024 + kc * 32);
#pragma unroll
  for (int di = 0; di < 4; ++di)
#pragma unroll
    for (int kc = 0; kc < 2; ++kc)
      vf[di][kc] = *(const bf16x8*)(Vrow + di * 32768 + kc * 32);

  const f32x4 FZ = (f32x4){0.f, 0.f, 0.f, 0.f};
  f32x4 oacc[4][4];  // [di][qi]
#pragma unroll
  for (int di = 0; di < 4; ++di)
#pragma unroll
    for (int qi = 0; qi < 4; ++qi) oacc[di][qi] = FZ;
  float lsum[4] = {0.f, 0.f, 0.f, 0.f};
  i32x4 pkP[4][2];

  for (int kt = 0; kt < 32; ++kt) {
    // S^T(kt) = K * Q^T, then exp2 -> packed P^T, per 16-q column group
#pragma unroll
    for (int qi = 0; qi < 4; ++qi) {
      f32x4 sacc[4];
#pragma unroll
      for (int ki = 0; ki < 4; ++ki)
        sacc[ki] = __builtin_amdgcn_mfma_f32_16x16x32_bf16(kf[ki][0], qf[qi][0], FZ, 0, 0, 0);
#pragma unroll
      for (int ki = 0; ki < 4; ++ki)
        sacc[ki] = __builtin_amdgcn_mfma_f32_16x16x32_bf16(kf[ki][1], qf[qi][1], sacc[ki], 0, 0, 0);
      float ls = 0.f;
#pragma unroll
      for (int kc = 0; kc < 2; ++kc)
#pragma unroll
        for (int u = 0; u < 2; ++u) {
          int ki = kc * 2 + u;
          float p0 = __builtin_amdgcn_exp2f(sacc[ki][0]);
          float p1 = __builtin_amdgcn_exp2f(sacc[ki][1]);
          float p2 = __builtin_amdgcn_exp2f(sacc[ki][2]);
          float p3 = __builtin_amdgcn_exp2f(sacc[ki][3]);
          ls += (p0 + p1) + (p2 + p3);
          pkP[qi][kc][u * 2 + 0] = pkbf16(p0, p1);
          pkP[qi][kc][u * 2 + 1] = pkbf16(p2, p3);
        }
      lsum[qi] += ls;
    }

    // prefetch kf(kt+1) — WAR-safe (after all kf uses); in flight during PV
    {
      const unsigned short* Kn = Krow + (size_t)(kt + 1) * 4096;
#pragma unroll
      for (int ki = 0; ki < 4; ++ki)
#pragma unroll
        for (int kc = 0; kc < 2; ++kc)
          kf[ki][kc] = *(const bf16x8*)(Kn + ki * 1024 + kc * 32);
    }

    // O^T += V^T * P^T
#pragma unroll
    for (int kc = 0; kc < 2; ++kc)
#pragma unroll
      for (int di = 0; di < 4; ++di)
#pragma unroll
        for (int qi = 0; qi < 4; ++qi)
          oacc[di][qi] = __builtin_amdgcn_mfma_f32_16x16x32_bf16(
              vf[di][kc], __builtin_bit_cast(bf16x8, pkP[qi][kc]), oacc[di][qi], 0, 0, 0);

    // prefetch vf(kt+1) — in flight during next S+exp
    {
      const unsigned short* Vn = Vrow + (kt + 1) * 64;
#pragma unroll
      for (int di = 0; di < 4; ++di)
#pragma unroll
        for (int kc = 0; kc < 2; ++kc)
          vf[di][kc] = *(const bf16x8*)(Vn + di * 32768 + kc * 32);
    }
  }

  // epilogue: O^T/l -> Og[b*2048+q][h*64+d]. l: sum partial quads via shuffle.
  const int b = bh >> 4, h = bh & 15;
#pragma unroll
  for (int qi = 0; qi < 4; ++qi) {
    float l = lsum[qi];
    l += __shfl_xor(l, 16);
    l += __shfl_xor(l, 32);
    float inv = 1.f / l;
    int q = q0 + qi * 16 + l15;
#pragma unroll
    for (int di = 0; di < 4; ++di) {
      unsigned int lo = (unsigned int)fbits(0.f);  // placeholder, overwritten
      lo = (unsigned int)pkbf16(oacc[di][qi][0] * inv, oacc[di][qi][1] * inv);
      unsigned int hi = (unsigned int)pkbf16(oacc[di][qi][2] * inv, oacc[di][qi][3] * inv);
      uint2 st; st.x = lo; st.y = hi;
      *(uint2*)(Og + ((size_t)(b * 2048 + q) * 1024) + h * 64 + di * 16 + quad * 4) = st;
    }
  }
}

extern "C" void kernel_launch(void* const* d_in, const int* in_sizes, int n_in,
                              void* d_out, int out_size, void* d_ws, size_t ws_size,
                              hipStream_t stream) {
  const float* x  = (const float*)d_in[0];
  const float* wq = (const float*)d_in[1];
  const float* bq = (const float*)d_in[2];
  const float* wk = (const float*)d_in[3];
  const float* bk = (const float*)d_in[4];
  const float* wv = (const float*)d_in[5];
  const float* bv = (const float*)d_in[6];
  const float* wo = (const float*)d_in[7];
  const float* bo = (const float*)d_in[8];
  char* ws = (char*)d_ws;
  unsigned short* Xb    = (unsigned short*)(ws);                      // 16 MB
  unsigned short* Wqkvt = (unsigned short*)(ws + (16ull << 20));      // 6 MB
  unsigned short* Wot   = (unsigned short*)(ws + (22ull << 20));      // 2 MB
  unsigned short* Qg    = (unsigned short*)(ws + (24ull << 20));      // 16 MB
  unsigned short* Kg    = (unsigned short*)(ws + (40ull << 20));      // 16 MB
  unsigned short* Vtg   = (unsigned short*)(ws + (56ull << 20));      // 16 MB
  unsigned short* Og    = (unsigned short*)(ws + (72ull << 20));      // 16 MB

  pack_all_kernel<<<9216, 256, 0, stream>>>(x, wq, wk, wv, wo, Xb, Wqkvt, Wot);
  gemm_bt_kernel<0><<<dim3(64, 24), 256, 0, stream>>>(Xb, Wqkvt, bq, bk, bv,
                                                      Qg, Kg, Vtg, nullptr);
  attn_kernel<<<512, 256, 0, stream>>>(Qg, Kg, Vtg, Og);
  gemm_bt_kernel<1><<<dim3(64, 8), 256, 0, stream>>>(Og, Wot, bo, nullptr, nullptr,
                                                     nullptr, nullptr, nullptr,
                                                     (float*)d_out);
}

// Round 7
// 247.927 us; speedup vs baseline: 1.2595x; 1.2595x over previous
//
#include <hip/hip_runtime.h>
#include <cstdint>

// Problem: B=4, S=2048, D_MODEL=1024, H=16, depth=64.
// Pipeline: pack x->bf16 + pack/transpose W->bf16 [N][K] (one launch);
// QKV GEMM (bf16 MFMA, fp32 acc, single-barrier double-buffered K-loop,
// C^T orientation for Q/K -> vectorized stores) -> Q[bh,s,d] (pre-scaled by
// log2e/8), K[bh,s,d], Vt[bh,d,s'] key-permuted; flash attention HYBRID:
// 64 q-rows/wave (256/block), Q direct global->VGPR, K/V LDS double-buffered;
// out GEMM (C^T, float4) -> fp32.

typedef __bf16 bf16x8 __attribute__((ext_vector_type(8)));
typedef float f32x4 __attribute__((ext_vector_type(4)));
typedef int i32x4 __attribute__((ext_vector_type(4)));

#define CEXP 0.18033688011112042f  // (1/8) * log2(e), folded into Q

__device__ __forceinline__ unsigned short f2bf(float f) {
  union { float f; unsigned int u; } v; v.f = f;
  unsigned int r = v.u + 0x7FFFu + ((v.u >> 16) & 1u);  // RNE
  return (unsigned short)(r >> 16);
}
__device__ __forceinline__ unsigned int fbits(float f) {
  union { float f; unsigned int u; } v; v.f = f; return v.u;
}

// pack two f32 -> one int holding (bf16(b)<<16)|bf16(a)
__device__ __forceinline__ int pkbf16(float a, float b) {
#if __has_builtin(__builtin_amdgcn_cvt_pk_bf16_f32)
  auto r = __builtin_amdgcn_cvt_pk_bf16_f32(a, b);  // lo=cvt(a), hi=cvt(b), RNE
  return __builtin_bit_cast(int, r);
#else
  return (int)__builtin_amdgcn_perm(fbits(b) + 0x8000u, fbits(a) + 0x8000u, 0x07060302u);
#endif
}

// async global->LDS, 16B per lane. LDS dest = wave-uniform base + lane*16.
__device__ __forceinline__ void gl_lds16(const void* g, void* l) {
  __builtin_amdgcn_global_load_lds(
      (const __attribute__((address_space(1))) void*)(unsigned long long)g,
      (__attribute__((address_space(3))) void*)(unsigned int)(unsigned long long)l,
      16, 0, 0);
}

// ---------------- pack x (fp32 -> bf16) + pack/transpose weights ----------------
__global__ __launch_bounds__(256) void pack_all_kernel(const float* __restrict__ x,
                                                       const float* __restrict__ wq,
                                                       const float* __restrict__ wk,
                                                       const float* __restrict__ wv,
                                                       const float* __restrict__ wo,
                                                       unsigned short* __restrict__ xb,
                                                       unsigned short* __restrict__ wqkvt,
                                                       unsigned short* __restrict__ wot) {
  int bid = blockIdx.x;
  if (bid < 8192) {  // pack x
    int i = (bid * 256 + threadIdx.x) * 4;
    float4 v = *(const float4*)(x + i);
    unsigned int lo = (unsigned int)f2bf(v.x) | ((unsigned int)f2bf(v.y) << 16);
    unsigned int hi = (unsigned int)f2bf(v.z) | ((unsigned int)f2bf(v.w) << 16);
    uint2 st; st.x = lo; st.y = hi;
    *(uint2*)(xb + i) = st;
    return;
  }
  // pack + transpose weights: Wt[n][k] = w[k][n]
  __shared__ unsigned short T[64 * 66];  // +2 pad: conflict-free
  bid -= 8192;
  int mat = bid >> 8;                    // 0..3 = wq,wk,wv,wo
  int tile = bid & 255;
  int tk = tile >> 4, tn = tile & 15;    // 64x64 tiles
  const float* W = (mat == 0) ? wq : (mat == 1) ? wk : (mat == 2) ? wv : wo;
  int t = threadIdx.x;
#pragma unroll
  for (int p = 0; p < 16; ++p) {
    int e = p * 256 + t;
    int r = e >> 6, c = e & 63;
    T[c * 66 + r] = f2bf(W[(tk * 64 + r) * 1024 + tn * 64 + c]);
  }
  __syncthreads();
  unsigned short* dst = (mat < 3) ? (wqkvt + mat * 1024 * 1024) : wot;
#pragma unroll
  for (int p = 0; p < 16; ++p) {
    int e = p * 256 + t;
    int nn = e >> 6, kk = e & 63;
    dst[(tn * 64 + nn) * 1024 + tk * 64 + kk] = T[nn * 66 + kk];
  }
}

// stage one 128x64 A-tile and 128x64 B-tile (swizzled) via global_load_lds
__device__ __forceinline__ void stage_tile(const unsigned short* __restrict__ Ag,
                                           const unsigned short* __restrict__ Bg,
                                           unsigned short* As, unsigned short* Bs,
                                           int t, int wave) {
#pragma unroll
  for (int p = 0; p < 4; ++p) {
    int s = p * 256 + t;
    int row = s >> 3;
    int cc = (s & 7) ^ (row & 7);
    gl_lds16(Ag + row * 1024 + cc * 8, (void*)(As + (p * 256 + wave * 64) * 8));
    gl_lds16(Bg + row * 1024 + cc * 8, (void*)(Bs + (p * 256 + wave * 64) * 8));
  }
}

// K-loop: acc = A-tile x B-tile^T over K=1024. TRANS=1 computes C^T
// (lane = m-row, regs = 4 consecutive n) for vectorized epilogue stores.
template <int TRANS>
__device__ __forceinline__ void kloop(const unsigned short* __restrict__ Ab,
                                      const unsigned short* __restrict__ Bb,
                                      unsigned short* S, f32x4 acc[4][4],
                                      int t, int wave, int l15, int quad,
                                      int wm, int wn, int Xo0, int Xo1) {
  stage_tile(Ab, Bb, S, S + 8192, t, wave);  // tile 0 -> buf 0
  for (int k0 = 0; k0 < 1024; k0 += 64) {
    const int buf = (k0 >> 6) & 1;
    unsigned short* Sc = S + buf * 16384;
    __syncthreads();  // drains buf's loads (issued one full iteration ago)
    if (k0 < 1024 - 64) {
      unsigned short* Sn = S + (buf ^ 1) * 16384;
      stage_tile(Ab + k0 + 64, Bb + k0 + 64, Sn, Sn + 8192, t, wave);
    }
#pragma unroll
    for (int kc = 0; kc < 2; ++kc) {
      const int Xo = kc ? Xo1 : Xo0;
      bf16x8 af[4], bfr[4];
#pragma unroll
      for (int mi = 0; mi < 4; ++mi)
        af[mi] = *(const bf16x8*)&Sc[(wm * 64 + mi * 16 + l15) * 64 + Xo];
#pragma unroll
      for (int ni = 0; ni < 4; ++ni)
        bfr[ni] = *(const bf16x8*)&Sc[8192 + (wn * 64 + ni * 16 + l15) * 64 + Xo];
#pragma unroll
      for (int mi = 0; mi < 4; ++mi)
#pragma unroll
        for (int ni = 0; ni < 4; ++ni)
          acc[mi][ni] = TRANS
              ? __builtin_amdgcn_mfma_f32_16x16x32_bf16(bfr[ni], af[mi], acc[mi][ni], 0, 0, 0)
              : __builtin_amdgcn_mfma_f32_16x16x32_bf16(af[mi], bfr[ni], acc[mi][ni], 0, 0, 0);
    }
  }
}

// ---------------- GEMM: C[M][N] = A[M][1024] * Bt[N][1024]^T ----------------
// MODE 0: QKV epilogue (bias + scatter bf16 to Q/K/Vt; Q pre-scaled by CEXP;
//         Vt key order permuted within 64-blocks).  MODE 1: fp32 out + bias.
template <int MODE>
__global__ __launch_bounds__(256) void gemm_bt_kernel(
    const unsigned short* __restrict__ A, const unsigned short* __restrict__ Bt,
    const float* __restrict__ b0, const float* __restrict__ b1, const float* __restrict__ b2,
    unsigned short* __restrict__ Qg, unsigned short* __restrict__ Kg,
    unsigned short* __restrict__ Vtg, float* __restrict__ Of) {
  __shared__ __align__(16) unsigned short S[32768];  // 64KB: [buf][A 8192 | B 8192]
  const int t = threadIdx.x;
  const int lane = t & 63, wave = t >> 6;
  const int l15 = lane & 15, quad = lane >> 4;
  const int wm = wave & 1, wn = wave >> 1;
  const int m0 = blockIdx.x * 128, n0 = blockIdx.y * 128;
  const unsigned short* Ab = A + (size_t)m0 * 1024;
  const unsigned short* Bb = Bt + (size_t)n0 * 1024;
  const int seg = (MODE == 0) ? (blockIdx.y >> 3) : 0;  // 0=Q,1=K,2=V

  f32x4 acc[4][4];
#pragma unroll
  for (int i = 0; i < 4; ++i)
#pragma unroll
    for (int j = 0; j < 4; ++j) acc[i][j] = (f32x4){0.f, 0.f, 0.f, 0.f};

  const int Xo0 = ((quad ^ (l15 & 7)) * 8);
  const int Xo1 = (((4 + quad) ^ (l15 & 7)) * 8);

  if (MODE == 1 || seg < 2) {  // block-uniform branch
    kloop<1>(Ab, Bb, S, acc, t, wave, l15, quad, wm, wn, Xo0, Xo1);
    if (MODE == 0) {
      // C^T: lane=m (s row), regs = 4 consecutive n (d) -> 8B stores
      const float* bias = (seg == 0) ? b0 : b1;
      unsigned short* qk = (seg == 0) ? Qg : Kg;
      const int m = m0 + wm * 64 + l15;
#pragma unroll
      for (int mi = 0; mi < 4; ++mi) {
        int mm = m + mi * 16;
        int b = mm >> 11, s = mm & 2047;
#pragma unroll
        for (int ni = 0; ni < 4; ++ni) {
          int nb = n0 + wn * 64 + ni * 16 + quad * 4;
          int nn = nb & 1023;
          float4 bb = *(const float4*)(bias + nn);
          int h = nn >> 6, d = nn & 63;
          float v0 = acc[mi][ni][0] + bb.x, v1 = acc[mi][ni][1] + bb.y;
          float v2 = acc[mi][ni][2] + bb.z, v3 = acc[mi][ni][3] + bb.w;
          if (seg == 0) { v0 *= CEXP; v1 *= CEXP; v2 *= CEXP; v3 *= CEXP; }
          uint2 st;
          st.x = (unsigned int)pkbf16(v0, v1);
          st.y = (unsigned int)pkbf16(v2, v3);
          *(uint2*)(qk + ((size_t)((b * 16 + h) * 2048 + s)) * 64 + d) = st;
        }
      }
    } else {
      // out-proj: float4 stores to Of[m][n..n+3]
      const int m = m0 + wm * 64 + l15;
#pragma unroll
      for (int mi = 0; mi < 4; ++mi) {
        int mm = m + mi * 16;
#pragma unroll
        for (int ni = 0; ni < 4; ++ni) {
          int n = n0 + wn * 64 + ni * 16 + quad * 4;
          float4 bb = *(const float4*)(b0 + n);
          float4 st;
          st.x = acc[mi][ni][0] + bb.x; st.y = acc[mi][ni][1] + bb.y;
          st.z = acc[mi][ni][2] + bb.z; st.w = acc[mi][ni][3] + bb.w;
          *(float4*)(Of + (size_t)mm * 1024 + n) = st;
        }
      }
    }
  } else {  // V: normal orientation; regs = 4 consecutive permuted key slots
    kloop<0>(Ab, Bb, S, acc, t, wave, l15, quad, wm, wn, Xo0, Xo1);
#pragma unroll
    for (int ni = 0; ni < 4; ++ni) {
      int n = n0 + wn * 64 + ni * 16 + l15;
      int nn = n & 1023;
      int h = nn >> 6, d = nn & 63;
      float bb = b2[nn];
#pragma unroll
      for (int mi = 0; mi < 4; ++mi) {
        int mb = m0 + wm * 64 + mi * 16 + quad * 4;
        int b = mb >> 11, s0 = mb & 2047;
        // key permutation keeps low 2 bits: 4 consecutive slots
        int sp0 = (s0 & ~63) | (s0 & 32) | ((s0 & 12) << 1) | ((s0 & 16) >> 2);
        float v0 = acc[mi][ni][0] + bb, v1 = acc[mi][ni][1] + bb;
        float v2 = acc[mi][ni][2] + bb, v3 = acc[mi][ni][3] + bb;
        uint2 st;
        st.x = (unsigned int)pkbf16(v0, v1);
        st.y = (unsigned int)pkbf16(v2, v3);
        *(uint2*)(Vtg + ((size_t)((b * 16 + h) * 64 + d)) * 2048 + sp0) = st;
      }
    }
  }
}

// ---------------- flash attention HYBRID ----------------
// grid: 512 blocks = 64 bh x 8 q-tiles of 256; 4 waves, wave owns 64 q rows.
// Q fragments direct global->VGPR (loop-invariant). K/V staged in LDS,
// double-buffered, prefetched one kt ahead (single barrier per kt).
// Per kt (64 keys): S^T = K*Q^T (4 qi groups); p = exp2(s) (scale pre-folded
// into Q); P^T packed in regs = PV B-operand (V^T global key order
// pre-permuted to match); O^T += V^T * P^T. lsum on VALU.
__global__ __launch_bounds__(256, 2) void attn_kernel(const unsigned short* __restrict__ Qg,
                                                      const unsigned short* __restrict__ Kg,
                                                      const unsigned short* __restrict__ Vtg,
                                                      unsigned short* __restrict__ Og) {
  __shared__ __align__(16) unsigned short smem[16384];  // 32KB: K0@0,V0@4096,K1@8192,V1@12288
  const int t = threadIdx.x;
  const int lane = t & 63, wave = t >> 6;
  const int l15 = lane & 15, quad = lane >> 4;
  const int bid = blockIdx.x;
  const int bh = (bid & 7) * 8 + (bid >> 6);  // XCD-affinity: same bh -> same XCD
  const int qt = (bid >> 3) & 7;
  const int q0 = qt * 256 + wave * 64;

  const unsigned short* Kh = Kg + (size_t)bh * 2048 * 64;
  const unsigned short* Vth = Vtg + (size_t)bh * 64 * 2048;

  // loop-invariant Q fragments, direct global->VGPR (B-operand: lane=q, elems=d)
  const unsigned short* Qrow = Qg + ((size_t)bh * 2048 + q0) * 64 + l15 * 64 + quad * 8;
  bf16x8 qf[4][2];
#pragma unroll
  for (int qi = 0; qi < 4; ++qi)
#pragma unroll
    for (int kc = 0; kc < 2; ++kc)
      qf[qi][kc] = *(const bf16x8*)(Qrow + qi * 1024 + kc * 32);

  // stage K/V tile 0 -> buf0
#pragma unroll
  for (int p = 0; p < 2; ++p) {
    int s = p * 256 + t;
    int row = s >> 3, cc = (s & 7) ^ (row & 7);
    gl_lds16(Kh + row * 64 + cc * 8, (void*)(smem + (p * 256 + wave * 64) * 8));
    gl_lds16(Vth + row * 2048 + cc * 8, (void*)(smem + 4096 + (p * 256 + wave * 64) * 8));
  }

  const int Xo0 = ((quad ^ (l15 & 7)) * 8);
  const int Xo1 = (((4 + quad) ^ (l15 & 7)) * 8);

  const f32x4 FZ = (f32x4){0.f, 0.f, 0.f, 0.f};
  f32x4 oacc[4][4];  // [di][qi]
#pragma unroll
  for (int di = 0; di < 4; ++di)
#pragma unroll
    for (int qi = 0; qi < 4; ++qi) oacc[di][qi] = FZ;
  float lsum[4] = {0.f, 0.f, 0.f, 0.f};

  for (int kt = 0; kt < 32; ++kt) {
    __syncthreads();  // buf[kt&1] loads drained; prior compute on buf[kt&1^1] done
    if (kt < 31) {
      const unsigned short* Kn = Kh + (kt + 1) * 4096;
      const unsigned short* Vn = Vth + (kt + 1) * 64;
      unsigned short* nb = smem + (((kt + 1) & 1) ? 8192 : 0);
#pragma unroll
      for (int p = 0; p < 2; ++p) {
        int s = p * 256 + t;
        int row = s >> 3, cc = (s & 7) ^ (row & 7);
        gl_lds16(Kn + row * 64 + cc * 8, (void*)(nb + (p * 256 + wave * 64) * 8));
        gl_lds16(Vn + row * 2048 + cc * 8, (void*)(nb + 4096 + (p * 256 + wave * 64) * 8));
      }
    }
    const unsigned short* Ks = smem + ((kt & 1) ? 8192 : 0);
    const unsigned short* Vs = Ks + 4096;

    // K fragments once, reused across 4 qi groups
    bf16x8 kf[4][2];
#pragma unroll
    for (int ki = 0; ki < 4; ++ki) {
      kf[ki][0] = *(const bf16x8*)&Ks[(ki * 16 + l15) * 64 + Xo0];
      kf[ki][1] = *(const bf16x8*)&Ks[(ki * 16 + l15) * 64 + Xo1];
    }

    // S^T(kt) = K * Q^T; exp2 -> packed P^T per qi
    i32x4 pkP[4][2];
#pragma unroll
    for (int qi = 0; qi < 4; ++qi) {
      f32x4 sacc[4];
#pragma unroll
      for (int ki = 0; ki < 4; ++ki)
        sacc[ki] = __builtin_amdgcn_mfma_f32_16x16x32_bf16(kf[ki][0], qf[qi][0], FZ, 0, 0, 0);
#pragma unroll
      for (int ki = 0; ki < 4; ++ki)
        sacc[ki] = __builtin_amdgcn_mfma_f32_16x16x32_bf16(kf[ki][1], qf[qi][1], sacc[ki], 0, 0, 0);
      float ls = 0.f;
#pragma unroll
      for (int kc = 0; kc < 2; ++kc)
#pragma unroll
        for (int u = 0; u < 2; ++u) {
          int ki = kc * 2 + u;
          float p0 = __builtin_amdgcn_exp2f(sacc[ki][0]);
          float p1 = __builtin_amdgcn_exp2f(sacc[ki][1]);
          float p2 = __builtin_amdgcn_exp2f(sacc[ki][2]);
          float p3 = __builtin_amdgcn_exp2f(sacc[ki][3]);
          ls += (p0 + p1) + (p2 + p3);
          pkP[qi][kc][u * 2 + 0] = pkbf16(p0, p1);
          pkP[qi][kc][u * 2 + 1] = pkbf16(p2, p3);
        }
      lsum[qi] += ls;
    }

    // O^T += V^T * P^T
#pragma unroll
    for (int kc = 0; kc < 2; ++kc) {
      const int Xo = kc ? Xo1 : Xo0;
      bf16x8 vf[4];
#pragma unroll
      for (int di = 0; di < 4; ++di)
        vf[di] = *(const bf16x8*)&Vs[(di * 16 + l15) * 64 + Xo];
#pragma unroll
      for (int di = 0; di < 4; ++di)
#pragma unroll
        for (int qi = 0; qi < 4; ++qi)
          oacc[di][qi] = __builtin_amdgcn_mfma_f32_16x16x32_bf16(
              vf[di], __builtin_bit_cast(bf16x8, pkP[qi][kc]), oacc[di][qi], 0, 0, 0);
    }
  }

  // epilogue: O^T/l -> Og[b*2048+q][h*64+d]. l: reduce across quads.
  const int b = bh >> 4, h = bh & 15;
#pragma unroll
  for (int qi = 0; qi < 4; ++qi) {
    float l = lsum[qi];
    l += __shfl_xor(l, 16);
    l += __shfl_xor(l, 32);
    float inv = 1.f / l;
    int q = q0 + qi * 16 + l15;
#pragma unroll
    for (int di = 0; di < 4; ++di) {
      unsigned int lo = (unsigned int)pkbf16(oacc[di][qi][0] * inv, oacc[di][qi][1] * inv);
      unsigned int hi = (unsigned int)pkbf16(oacc[di][qi][2] * inv, oacc[di][qi][3] * inv);
      uint2 st; st.x = lo; st.y = hi;
      *(uint2*)(Og + ((size_t)(b * 2048 + q) * 1024) + h * 64 + di * 16 + quad * 4) = st;
    }
  }
}

extern "C" void kernel_launch(void* const* d_in, const int* in_sizes, int n_in,
                              void* d_out, int out_size, void* d_ws, size_t ws_size,
                              hipStream_t stream) {
  const float* x  = (const float*)d_in[0];
  const float* wq = (const float*)d_in[1];
  const float* bq = (const float*)d_in[2];
  const float* wk = (const float*)d_in[3];
  const float* bk = (const float*)d_in[4];
  const float* wv = (const float*)d_in[5];
  const float* bv = (const float*)d_in[6];
  const float* wo = (const float*)d_in[7];
  const float* bo = (const float*)d_in[8];
  char* ws = (char*)d_ws;
  unsigned short* Xb    = (unsigned short*)(ws);                      // 16 MB
  unsigned short* Wqkvt = (unsigned short*)(ws + (16ull << 20));      // 6 MB
  unsigned short* Wot   = (unsigned short*)(ws + (22ull << 20));      // 2 MB
  unsigned short* Qg    = (unsigned short*)(ws + (24ull << 20));      // 16 MB
  unsigned short* Kg    = (unsigned short*)(ws + (40ull << 20));      // 16 MB
  unsigned short* Vtg   = (unsigned short*)(ws + (56ull << 20));      // 16 MB
  unsigned short* Og    = (unsigned short*)(ws + (72ull << 20));      // 16 MB

  pack_all_kernel<<<9216, 256, 0, stream>>>(x, wq, wk, wv, wo, Xb, Wqkvt, Wot);
  gemm_bt_kernel<0><<<dim3(64, 24), 256, 0, stream>>>(Xb, Wqkvt, bq, bk, bv,
                                                      Qg, Kg, Vtg, nullptr);
  attn_kernel<<<512, 256, 0, stream>>>(Qg, Kg, Vtg, Og);
  gemm_bt_kernel<1><<<dim3(64, 8), 256, 0, stream>>>(Og, Wot, bo, nullptr, nullptr,
                                                     nullptr, nullptr, nullptr,
                                                     (float*)d_out);
}